// Round 1
// baseline (578.064 us; speedup 1.0000x reference)
//
#include <hip/hip_runtime.h>
#include <math.h>

// Problem constants (fixed by setup_inputs): B=2, N=1024, H=8, G=8
#define BB 2
#define NN 1024
#define HG 64            // H*G
#define NBATCH (BB*HG)   // 128 (b,h,g) batches
#define DD 16             // SH dim 15, padded to 16 floats (64 B rows)

// Kernel 1: rotate (R @ v), normalize, spherical-harmonic expand (l=1,2,3),
// write Y[batch][n][16] with batch=(b*8+h)*8+g. `scale` folds 1/sqrt(15)
// into the q side so the GEMM needs no epilogue scaling.
__global__ __launch_bounds__(256) void sh_kernel(
    const float* __restrict__ v_in,   // [B,N,H,G,3]
    const float* __restrict__ R_in,   // [B,N,3,3]
    float* __restrict__ Y,            // [NBATCH][NN][DD]
    float scale)
{
    int t = blockIdx.x * 256 + threadIdx.x;      // linear over [B,N,H,G]
    int g = t & 7;
    int h = (t >> 3) & 7;
    int n = (t >> 6) & (NN - 1);
    int b = t >> 16;

    const float* vp = v_in + (size_t)t * 3;
    float vx = vp[0], vy = vp[1], vz = vp[2];
    const float* Rp = R_in + ((size_t)(b * NN + n)) * 9;
    // out_i = sum_j R[i][j] * v[j]
    float x = Rp[0]*vx + Rp[1]*vy + Rp[2]*vz;
    float y = Rp[3]*vx + Rp[4]*vy + Rp[5]*vz;
    float z = Rp[6]*vx + Rp[7]*vy + Rp[8]*vz;
    float nrm = sqrtf(x*x + y*y + z*z);
    float inv = 1.0f / fmaxf(nrm, 1e-12f);
    x *= inv; y *= inv; z *= inv;
    float x2 = x*x, y2 = y*y, z2 = z*z;

    const float s3  = 1.7320508075688772f;   // sqrt(3)
    const float s15 = 3.8729833462074170f;   // sqrt(15)
    const float c1  = 0.6123724356957945f;   // sqrt(3/8)
    const float c3  = 0.7905694150420949f;   // sqrt(5/8)
    float f1 = 0.4886025119029199f * scale;  // sqrt(3/(4pi))
    float f2 = 0.6307831305050401f * scale;  // sqrt(5/(4pi))
    float f3 = 0.7463526651802308f * scale;  // sqrt(7/(4pi))

    float4 o0, o1, o2, o3;
    // l=1
    o0.x = f1 * x;
    o0.y = f1 * y;
    o0.z = f1 * z;
    // l=2
    o0.w = f2 * (s3 * x * z);
    o1.x = f2 * (s3 * x * y);
    o1.y = f2 * (y2 - 0.5f*(x2 + z2));
    o1.z = f2 * (s3 * y * z);
    o1.w = f2 * (0.5f * s3 * (z2 - x2));
    // l=3
    o2.x = f3 * (c3 * x * (3.0f*z2 - x2));
    o2.y = f3 * (s15 * x * y * z);
    o2.z = f3 * (c1 * x * (4.0f*y2 - x2 - z2));
    o2.w = f3 * (0.5f * y * (2.0f*y2 - 3.0f*x2 - 3.0f*z2));
    o3.x = f3 * (c1 * z * (4.0f*y2 - x2 - z2));
    o3.y = f3 * (0.5f * s15 * y * (z2 - x2));
    o3.z = f3 * (c3 * z * (z2 - 3.0f*x2));
    o3.w = 0.0f;  // pad

    int batch = (b << 6) | (h << 3) | g;
    float4* out = (float4*)(Y + ((size_t)batch * NN + n) * DD);
    out[0] = o0; out[1] = o1; out[2] = o2; out[3] = o3;  // one aligned 64-B line/thread
}

// Kernel 2: per-batch scores[n][m] = sum_d Yq[n][d]*Yk[m][d].
// One 64x64 output tile per block; LDS tiles stored transposed [d][64] so
// compute-phase float4 reads are <=2-way bank aliased (free on CDNA4).
__global__ __launch_bounds__(256) void score_kernel(
    const float* __restrict__ Yq,   // [NBATCH][NN][DD]  (already scaled by 1/sqrt15)
    const float* __restrict__ Yk,   // [NBATCH][NN][DD]
    float* __restrict__ out)        // [NBATCH][NN][NN]
{
    __shared__ float As[DD][64];
    __shared__ float Bs[DD][64];

    int bid   = blockIdx.x;
    int batch = bid >> 8;
    int n0    = ((bid >> 4) & 15) << 6;
    int m0    = (bid & 15) << 6;
    int t     = threadIdx.x;

    // Stage: each thread loads one float4 (row-major global) and transposes
    // into LDS (4 scalar writes, 4-way bank aliased -> negligible cost).
    int row = t >> 2;
    int dc  = (t & 3) << 2;
    float4 av = *(const float4*)(Yq + ((size_t)batch * NN + n0 + row) * DD + dc);
    float4 bv = *(const float4*)(Yk + ((size_t)batch * NN + m0 + row) * DD + dc);
    As[dc+0][row] = av.x; As[dc+1][row] = av.y; As[dc+2][row] = av.z; As[dc+3][row] = av.w;
    Bs[dc+0][row] = bv.x; Bs[dc+1][row] = bv.y; Bs[dc+2][row] = bv.z; Bs[dc+3][row] = bv.w;
    __syncthreads();

    int tx = (t & 15) << 2;   // m offset of 4-col micro-tile
    int ty = (t >> 4) << 2;   // n offset of 4-row micro-tile

    float acc[4][4];
    #pragma unroll
    for (int i = 0; i < 4; ++i)
        #pragma unroll
        for (int j = 0; j < 4; ++j) acc[i][j] = 0.0f;

    #pragma unroll
    for (int d = 0; d < 15; ++d) {   // d=15 is the zero pad, skip it
        float4 a4 = *(const float4*)&As[d][ty];
        float4 b4 = *(const float4*)&Bs[d][tx];
        acc[0][0] += a4.x*b4.x; acc[0][1] += a4.x*b4.y; acc[0][2] += a4.x*b4.z; acc[0][3] += a4.x*b4.w;
        acc[1][0] += a4.y*b4.x; acc[1][1] += a4.y*b4.y; acc[1][2] += a4.y*b4.z; acc[1][3] += a4.y*b4.w;
        acc[2][0] += a4.z*b4.x; acc[2][1] += a4.z*b4.y; acc[2][2] += a4.z*b4.z; acc[2][3] += a4.z*b4.w;
        acc[3][0] += a4.w*b4.x; acc[3][1] += a4.w*b4.y; acc[3][2] += a4.w*b4.z; acc[3][3] += a4.w*b4.w;
    }

    float* op = out + ((size_t)batch * NN + n0 + ty) * NN + m0 + tx;
    #pragma unroll
    for (int i = 0; i < 4; ++i) {
        float4 o; o.x = acc[i][0]; o.y = acc[i][1]; o.z = acc[i][2]; o.w = acc[i][3];
        *(float4*)(op + (size_t)i * NN) = o;
    }
}

extern "C" void kernel_launch(void* const* d_in, const int* in_sizes, int n_in,
                              void* d_out, int out_size, void* d_ws, size_t ws_size,
                              hipStream_t stream) {
    const float* q   = (const float*)d_in[0];
    const float* k   = (const float*)d_in[1];
    const float* r_q = (const float*)d_in[2];
    const float* r_k = (const float*)d_in[3];

    float* Yq = (float*)d_ws;                          // 8 MiB
    float* Yk = Yq + (size_t)NBATCH * NN * DD;         // 8 MiB
    float* out = (float*)d_out;

    const float inv_sqrt15 = 0.25819888974716112567f;  // fold 1/sqrt(d) into q side

    hipLaunchKernelGGL(sh_kernel, dim3((BB*NN*HG)/256), dim3(256), 0, stream,
                       q, r_q, Yq, inv_sqrt15);
    hipLaunchKernelGGL(sh_kernel, dim3((BB*NN*HG)/256), dim3(256), 0, stream,
                       k, r_k, Yk, 1.0f);
    hipLaunchKernelGGL(score_kernel, dim3(NBATCH * 16 * 16), dim3(256), 0, stream,
                       Yq, Yk, out);
}